// Round 6
// baseline (2735.879 us; speedup 1.0000x reference)
//
#include <hip/hip_runtime.h>

// GCN regression: out = relu( dinv⊙(A_hat @ (dinv⊙(x@W1^T))) + b1 ) @ W2^T + b2
// A_hat = adjacency (src->dst) + self loops; dinv = rsqrt(indeg+1).
//
// R4: bucketed aggregation replaces CSR.
//   1. count_kernel  : per-edge degc histogram + LDS bucket histogram (391 buckets)
//   2. bscan_kernel  : 1-block scan of bucket counts -> boff, bcur
//   3. gemm_kernel   : g = dinv ⊙ (x @ W1^T), stored bf16 (12.8 MB)
//   4. binfill_kernel: scatter packed edge (dl<<17|src) into bucket-major ebuf
//                      (391 write frontiers -> full-line writes, no 16x amplification)
//   5. agg_kernel    : block=bucket, LDS acc[256][64] f32, batched bf16 gather +
//                      LDS atomic adds, fused dinv/b1/relu/W2/b2 epilogue

typedef unsigned int u32;
typedef unsigned short u16;

__device__ __forceinline__ u16 f2bf(float f) {
    u32 b = __float_as_uint(f);
    b += 0x7FFF + ((b >> 16) & 1);   // round-to-nearest-even
    return (u16)(b >> 16);
}
__device__ __forceinline__ float bf2f(u16 u) {
    return __uint_as_float(((u32)u) << 16);
}

__device__ __forceinline__ int swz(int k, int cc) {
    int g = cc >> 2;
    int slot = (k << 4) + (g ^ (k & 15));
    return (slot << 2) + (cc & 3);
}

// ---- 1. degree + bucket count ----
__global__ __launch_bounds__(256) void count_kernel(const int* __restrict__ dst,
                                                    int* __restrict__ degc,
                                                    int* __restrict__ bcnt,
                                                    int E, int NB) {
    __shared__ int h[512];
    int t = threadIdx.x;
    for (int i = t; i < 512; i += 256) h[i] = 0;
    __syncthreads();
    for (int e = blockIdx.x * 256 + t; e < E; e += gridDim.x * 256) {
        int d = dst[e];
        atomicAdd(&degc[d], 1);
        atomicAdd(&h[d >> 8], 1);
    }
    __syncthreads();
    for (int i = t; i < NB; i += 256)
        if (h[i]) atomicAdd(&bcnt[i], h[i]);
}

// ---- 2. bucket scan (NB <= 512) ----
__global__ __launch_bounds__(512) void bscan_kernel(const int* __restrict__ bcnt,
                                                    int* __restrict__ boff,
                                                    int* __restrict__ bcur,
                                                    int NB, int E) {
    __shared__ int buf[2][512];
    int t = threadIdx.x;
    int v = (t < NB) ? bcnt[t] : 0;
    buf[0][t] = v;
    __syncthreads();
    int pi = 0;
    for (int d = 1; d < 512; d <<= 1) {
        int val = buf[pi][t];
        if (t >= d) val += buf[pi][t - d];
        buf[pi ^ 1][t] = val;
        pi ^= 1;
        __syncthreads();
    }
    if (t < NB) {
        int excl = buf[pi][t] - v;
        boff[t] = excl;
        bcur[t] = excl;
    }
    if (t == 0) boff[NB] = E;
}

// ---- 3. g = dinv * (x @ W1^T), bf16 out ----
__global__ __launch_bounds__(256) void gemm_kernel(const float* __restrict__ x,
                                                   const float* __restrict__ W1,
                                                   const int* __restrict__ degc,
                                                   u16* __restrict__ gb, int N) {
    __shared__ float xT[128 * 64];
    __shared__ float wT[128 * 64];
    int t = threadIdx.x;
    int nbase = blockIdx.x * 64;

    for (int i = t; i < 64 * 128; i += 256) {
        int c = i >> 7, k = i & 127;
        wT[swz(k, c)] = W1[i];
    }
    for (int it = 0; it < 8; ++it) {
        int node = it * 8 + (t >> 5);
        int k4 = (t & 31) << 2;
        int n = nbase + node;
        float4 v = make_float4(0.f, 0.f, 0.f, 0.f);
        if (n < N) v = *(const float4*)&x[(size_t)n * 128 + k4];
        xT[swz(k4 + 0, node)] = v.x;
        xT[swz(k4 + 1, node)] = v.y;
        xT[swz(k4 + 2, node)] = v.z;
        xT[swz(k4 + 3, node)] = v.w;
    }
    __syncthreads();

    int tx = t & 15;
    int ty = t >> 4;
    float acc[4][4] = {};
#pragma unroll 4
    for (int k = 0; k < 128; ++k) {
        float4 xv = *(const float4*)&xT[swz(k, ty << 2)];
        float4 wv = *(const float4*)&wT[swz(k, tx << 2)];
        float xa[4] = {xv.x, xv.y, xv.z, xv.w};
        float wa[4] = {wv.x, wv.y, wv.z, wv.w};
#pragma unroll
        for (int i2 = 0; i2 < 4; ++i2)
#pragma unroll
            for (int j2 = 0; j2 < 4; ++j2)
                acc[i2][j2] = fmaf(xa[i2], wa[j2], acc[i2][j2]);
    }

#pragma unroll
    for (int i2 = 0; i2 < 4; ++i2) {
        int n = nbase + (ty << 2) + i2;
        if (n < N) {
            float dv = rsqrtf((float)(degc[n] + 1));
            ushort4 o;
            o.x = f2bf(dv * acc[i2][0]);
            o.y = f2bf(dv * acc[i2][1]);
            o.z = f2bf(dv * acc[i2][2]);
            o.w = f2bf(dv * acc[i2][3]);
            *(ushort4*)&gb[(size_t)n * 64 + (tx << 2)] = o;
        }
    }
}

// ---- 4. bucket-major edge scatter ----
__global__ __launch_bounds__(256) void binfill_kernel(const int* __restrict__ src,
                                                      const int* __restrict__ dst,
                                                      int* __restrict__ bcur,
                                                      u32* __restrict__ ebuf, int E) {
    int e = blockIdx.x * 256 + threadIdx.x;
    if (e < E) {
        int d = dst[e];
        int s = src[e];
        int b = d >> 8;
        int p = atomicAdd(&bcur[b], 1);
        ebuf[p] = ((u32)(d & 255) << 17) | (u32)s;
    }
}

// ---- 5. per-bucket LDS aggregation + fused epilogue ----
__global__ __launch_bounds__(256) void agg_kernel(const u16* __restrict__ gb,
                                                  const u32* __restrict__ ebuf,
                                                  const int* __restrict__ boff,
                                                  const int* __restrict__ degc,
                                                  const float* __restrict__ W2,
                                                  const float* __restrict__ b1,
                                                  const float* __restrict__ b2,
                                                  float* __restrict__ out, int N) {
    __shared__ float acc[256 * 64];   // 64 KB
    int t = threadIdx.x;
    int lane = t & 63;
    int wv = t >> 6;
    int b = blockIdx.x;
    int base = b << 8;

    for (int i = t; i < 256 * 64; i += 256) acc[i] = 0.f;
    __syncthreads();

    int o0 = boff[b];
    int nE = boff[b + 1] - o0;
    const u32* eb = ebuf + o0;

    int nChunks = nE >> 6;
    for (int c = wv; c < nChunks; c += 4) {
        u32 pk = eb[c * 64 + lane];
#pragma unroll
        for (int j0 = 0; j0 < 64; j0 += 8) {
            float v[8];
            int dla[8];
#pragma unroll
            for (int k = 0; k < 8; ++k) {
                u32 e2 = (u32)__shfl((int)pk, j0 + k);
                int s = (int)(e2 & 0x1FFFF);
                dla[k] = (int)(e2 >> 17);
                v[k] = bf2f(gb[(size_t)s * 64 + lane]);
            }
#pragma unroll
            for (int k = 0; k < 8; ++k)
                atomicAdd(&acc[dla[k] * 64 + lane], v[k]);
        }
    }
    // tail (wave 0)
    int tail0 = nChunks << 6;
    int rem = nE - tail0;
    if (wv == 0 && rem > 0) {
        u32 pk = (lane < rem) ? eb[tail0 + lane] : 0u;
        for (int j = 0; j < rem; ++j) {
            u32 e2 = (u32)__shfl((int)pk, j);
            int s = (int)(e2 & 0x1FFFF);
            int dl = (int)(e2 >> 17);
            atomicAdd(&acc[dl * 64 + lane], bf2f(gb[(size_t)s * 64 + lane]));
        }
    }
    __syncthreads();

    // epilogue
    float w2 = W2[lane];
    float bb1 = b1[lane];
    float b2v = b2[0];
    int cnt = N - base;
    if (cnt > 256) cnt = 256;
    for (int dl = wv; dl < cnt; dl += 4) {
        int n = base + dl;
        float a = acc[dl * 64 + lane] + bf2f(gb[(size_t)n * 64 + lane]);  // self loop
        float dv = rsqrtf((float)(degc[n] + 1));
        float val = fmaxf(dv * a + bb1, 0.f) * w2;
#pragma unroll
        for (int o = 32; o >= 1; o >>= 1) val += __shfl_xor(val, o);
        if (lane == 0) out[n] = val + b2v;
    }
}

extern "C" void kernel_launch(void* const* d_in, const int* in_sizes, int n_in,
                              void* d_out, int out_size, void* d_ws, size_t ws_size,
                              hipStream_t stream) {
    const float* x  = (const float*)d_in[0];
    const int*   ei = (const int*)d_in[1];
    const float* W1 = (const float*)d_in[2];
    const float* b1 = (const float*)d_in[3];
    const float* W2 = (const float*)d_in[4];
    const float* b2 = (const float*)d_in[5];
    float* out = (float*)d_out;

    int N = in_sizes[0] / 128;
    int E = in_sizes[1] / 2;
    const int* src = ei;
    const int* dst = ei + E;
    int NB = (N + 255) >> 8;   // 391 for N=100000 (must be <= 512)

    char* ws = (char*)d_ws;
    int* degc = (int*)(ws + 0x000000);   // N ints (400 KB)
    int* bcnt = (int*)(ws + 0x080000);   // NB ints
    int* boff = (int*)(ws + 0x084000);   // NB+1 ints
    int* bcur = (int*)(ws + 0x088000);   // NB ints
    u32* ebuf = (u32*)(ws + 0x090000);   // E u32 (12.8 MB)
    u16* gb   = (u16*)(ws + 0xE00000);   // N*64 bf16 (12.8 MB)

    hipMemsetAsync(degc, 0, (size_t)N * 4, stream);
    hipMemsetAsync(bcnt, 0, (size_t)NB * 4, stream);

    count_kernel<<<1024, 256, 0, stream>>>(dst, degc, bcnt, E, NB);
    bscan_kernel<<<1, 512, 0, stream>>>(bcnt, boff, bcur, NB, E);
    gemm_kernel<<<(N + 63) / 64, 256, 0, stream>>>(x, W1, degc, gb, N);
    binfill_kernel<<<(E + 255) / 256, 256, 0, stream>>>(src, dst, bcur, ebuf, E);
    agg_kernel<<<NB, 256, 0, stream>>>(gb, ebuf, boff, degc, W2, b1, b2, out, N);
}

// Round 7
// 1394.615 us; speedup vs baseline: 1.9617x; 1.9617x over previous
//
#include <hip/hip_runtime.h>

// GCN regression: out = relu( dinv⊙(A_hat @ (dinv⊙(x@W1^T))) + b1 ) @ W2^T + b2
// R5: high-TLP CSR agg + bucket-staged CSR build.
//   1. deg_kernel    : in-degree histogram (1 atomic/edge)
//   2. scanA/B/C     : exclusive scan degc -> offs  (boff[b] == offs[b<<8])
//   3. bcini_kernel  : bcur[b] = offs[b<<8]
//   4. gemm_kernel   : g = dinv ⊙ (x @ W1^T) stored bf16 (12.8 MB)
//   5. binfill_kernel: scatter packed (dl<<17|src) into bucket-major ebuf
//   6. csrb_kernel   : per-bucket LDS scatter -> coalesced CSR span write
//   7. agg_kernel    : wave per node (100k waves), batched bf16 gathers,
//                      fused dinv/b1/relu/W2/b2 epilogue

typedef unsigned int u32;
typedef unsigned short u16;

#define SCB 512
#define CAP 12288   // max edges per 256-node bucket (mean 8192, sigma ~90)

__device__ __forceinline__ u16 f2bf(float f) {
    u32 b = __float_as_uint(f);
    b += 0x7FFF + ((b >> 16) & 1);
    return (u16)(b >> 16);
}
__device__ __forceinline__ float bf2f(u16 u) {
    return __uint_as_float(((u32)u) << 16);
}
__device__ __forceinline__ int swz(int k, int cc) {
    int g = cc >> 2;
    int slot = (k << 4) + (g ^ (k & 15));
    return (slot << 2) + (cc & 3);
}

__global__ __launch_bounds__(256) void deg_kernel(const int* __restrict__ dst,
                                                  int* __restrict__ degc, int E) {
    int e = blockIdx.x * 256 + threadIdx.x;
    if (e < E) atomicAdd(&degc[dst[e]], 1);
}

__global__ __launch_bounds__(SCB) void scanA_kernel(const int* __restrict__ degc,
                                                    int* __restrict__ offs,
                                                    int* __restrict__ csum, int N) {
    __shared__ int buf[2][SCB];
    int t = threadIdx.x;
    int i = blockIdx.x * SCB + t;
    int v = (i < N) ? degc[i] : 0;
    buf[0][t] = v;
    __syncthreads();
    int pi = 0;
    for (int d = 1; d < SCB; d <<= 1) {
        int val = buf[pi][t];
        if (t >= d) val += buf[pi][t - d];
        buf[pi ^ 1][t] = val;
        pi ^= 1;
        __syncthreads();
    }
    int incl = buf[pi][t];
    if (i < N) offs[i] = incl - v;
    if (t == SCB - 1) csum[blockIdx.x] = incl;
}

__global__ __launch_bounds__(256) void scanB_kernel(const int* __restrict__ csum,
                                                    int* __restrict__ cbase, int NCH) {
    __shared__ int buf[2][256];
    int t = threadIdx.x;
    int v = (t < NCH) ? csum[t] : 0;
    buf[0][t] = v;
    __syncthreads();
    int pi = 0;
    for (int d = 1; d < 256; d <<= 1) {
        int val = buf[pi][t];
        if (t >= d) val += buf[pi][t - d];
        buf[pi ^ 1][t] = val;
        pi ^= 1;
        __syncthreads();
    }
    if (t < NCH) cbase[t] = buf[pi][t] - v;
}

__global__ __launch_bounds__(SCB) void scanC_kernel(int* __restrict__ offs,
                                                    const int* __restrict__ cbase, int N) {
    int i = blockIdx.x * SCB + threadIdx.x;
    if (i < N) offs[i] += cbase[blockIdx.x];
}

__global__ __launch_bounds__(512) void bcini_kernel(const int* __restrict__ offs,
                                                    int* __restrict__ bcur, int NB) {
    int t = threadIdx.x;
    if (t < NB) bcur[t] = offs[t << 8];
}

__global__ __launch_bounds__(256) void gemm_kernel(const float* __restrict__ x,
                                                   const float* __restrict__ W1,
                                                   const int* __restrict__ degc,
                                                   u16* __restrict__ gb, int N) {
    __shared__ float xT[128 * 64];
    __shared__ float wT[128 * 64];
    int t = threadIdx.x;
    int nbase = blockIdx.x * 64;

    for (int i = t; i < 64 * 128; i += 256) {
        int c = i >> 7, k = i & 127;
        wT[swz(k, c)] = W1[i];
    }
    for (int it = 0; it < 8; ++it) {
        int node = it * 8 + (t >> 5);
        int k4 = (t & 31) << 2;
        int n = nbase + node;
        float4 v = make_float4(0.f, 0.f, 0.f, 0.f);
        if (n < N) v = *(const float4*)&x[(size_t)n * 128 + k4];
        xT[swz(k4 + 0, node)] = v.x;
        xT[swz(k4 + 1, node)] = v.y;
        xT[swz(k4 + 2, node)] = v.z;
        xT[swz(k4 + 3, node)] = v.w;
    }
    __syncthreads();

    int tx = t & 15;
    int ty = t >> 4;
    float acc[4][4] = {};
#pragma unroll 4
    for (int k = 0; k < 128; ++k) {
        float4 xv = *(const float4*)&xT[swz(k, ty << 2)];
        float4 wv = *(const float4*)&wT[swz(k, tx << 2)];
        float xa[4] = {xv.x, xv.y, xv.z, xv.w};
        float wa[4] = {wv.x, wv.y, wv.z, wv.w};
#pragma unroll
        for (int i2 = 0; i2 < 4; ++i2)
#pragma unroll
            for (int j2 = 0; j2 < 4; ++j2)
                acc[i2][j2] = fmaf(xa[i2], wa[j2], acc[i2][j2]);
    }

#pragma unroll
    for (int i2 = 0; i2 < 4; ++i2) {
        int n = nbase + (ty << 2) + i2;
        if (n < N) {
            float dv = rsqrtf((float)(degc[n] + 1));
            ushort4 o;
            o.x = f2bf(dv * acc[i2][0]);
            o.y = f2bf(dv * acc[i2][1]);
            o.z = f2bf(dv * acc[i2][2]);
            o.w = f2bf(dv * acc[i2][3]);
            *(ushort4*)&gb[(size_t)n * 64 + (tx << 2)] = o;
        }
    }
}

__global__ __launch_bounds__(256) void binfill_kernel(const int* __restrict__ src,
                                                      const int* __restrict__ dst,
                                                      int* __restrict__ bcur,
                                                      u32* __restrict__ ebuf, int E) {
    int e = blockIdx.x * 256 + threadIdx.x;
    if (e < E) {
        int d = dst[e];
        int s = src[e];
        int p = atomicAdd(&bcur[d >> 8], 1);
        ebuf[p] = ((u32)(d & 255) << 17) | (u32)s;
    }
}

// per-bucket: LDS scatter into exact CSR order, coalesced span write-back
__global__ __launch_bounds__(256) void csrb_kernel(const u32* __restrict__ ebuf,
                                                   const int* __restrict__ offs,
                                                   int* __restrict__ csr,
                                                   int N, int E, int NB) {
    __shared__ u32 stage[CAP];   // 48 KB
    __shared__ int cur[256];
    __shared__ int lofs[256];
    int t = threadIdx.x;
    int b = blockIdx.x;
    int base = b << 8;
    int b0 = offs[base];
    int nxt = base + 256;
    int b1 = (nxt >= N) ? E : offs[nxt];
    int cnt = b1 - b0;
    cur[t] = 0;
    int n = base + t;
    lofs[t] = (n < N) ? offs[n] - b0 : 0;
    __syncthreads();
    if (cnt <= CAP) {
        for (int e = t; e < cnt; e += 256) {
            u32 pk = ebuf[b0 + e];
            int dl = (int)(pk >> 17);
            int p = atomicAdd(&cur[dl], 1);
            stage[lofs[dl] + p] = pk & 0x1FFFF;
        }
        __syncthreads();
        for (int e = t; e < cnt; e += 256) csr[b0 + e] = (int)stage[e];
    } else {  // statistically unreachable fallback (correctness net)
        for (int e = t; e < cnt; e += 256) {
            u32 pk = ebuf[b0 + e];
            int dl = (int)(pk >> 17);
            int p = atomicAdd(&cur[dl], 1);
            csr[b0 + lofs[dl] + p] = (int)(pk & 0x1FFFF);
        }
    }
}

// wave per node: lane = channel; batched bf16 gathers; fused epilogue
__global__ __launch_bounds__(256) void agg_kernel(const u16* __restrict__ gb,
                                                  const int* __restrict__ csr,
                                                  const int* __restrict__ offs,
                                                  const int* __restrict__ degc,
                                                  const float* __restrict__ W2,
                                                  const float* __restrict__ b1,
                                                  const float* __restrict__ b2,
                                                  float* __restrict__ out, int N) {
    int wid = blockIdx.x * 4 + (threadIdx.x >> 6);
    int lane = threadIdx.x & 63;
    if (wid >= N) return;
    int off = offs[wid];
    int cnt = degc[wid];
    float acc = bf2f(gb[(size_t)wid * 64 + lane]);   // self loop
    for (int base = 0; base < cnt; base += 64) {
        int rem = cnt - base;
        if (rem > 64) rem = 64;
        int s = (lane < rem) ? csr[off + base + lane] : 0;
        int j = 0;
        for (; j + 8 <= rem; j += 8) {
            float v[8];
#pragma unroll
            for (int k = 0; k < 8; ++k) {
                int sj = __shfl(s, j + k);
                v[k] = bf2f(gb[(size_t)sj * 64 + lane]);
            }
            acc += ((v[0] + v[1]) + (v[2] + v[3])) + ((v[4] + v[5]) + (v[6] + v[7]));
        }
        for (; j < rem; ++j) {
            int sj = __shfl(s, j);
            acc += bf2f(gb[(size_t)sj * 64 + lane]);
        }
    }
    float dv = rsqrtf((float)(cnt + 1));
    float val = fmaxf(dv * acc + b1[lane], 0.f) * W2[lane];
#pragma unroll
    for (int o = 32; o >= 1; o >>= 1) val += __shfl_xor(val, o);
    if (lane == 0) out[wid] = val + b2[0];
}

extern "C" void kernel_launch(void* const* d_in, const int* in_sizes, int n_in,
                              void* d_out, int out_size, void* d_ws, size_t ws_size,
                              hipStream_t stream) {
    const float* x  = (const float*)d_in[0];
    const int*   ei = (const int*)d_in[1];
    const float* W1 = (const float*)d_in[2];
    const float* b1 = (const float*)d_in[3];
    const float* W2 = (const float*)d_in[4];
    const float* b2 = (const float*)d_in[5];
    float* out = (float*)d_out;

    int N = in_sizes[0] / 128;
    int E = in_sizes[1] / 2;
    const int* src = ei;
    const int* dst = ei + E;
    int NB = (N + 255) >> 8;            // 391
    int NCH = (N + SCB - 1) / SCB;      // 196

    char* ws = (char*)d_ws;
    int* degc  = (int*)(ws + 0x000000);   // N ints
    int* offs  = (int*)(ws + 0x080000);   // N ints
    int* bcur  = (int*)(ws + 0x100000);   // NB ints
    int* csum  = (int*)(ws + 0x104000);   // NCH ints
    int* cbase = (int*)(ws + 0x108000);   // NCH ints
    u32* ebuf  = (u32*)(ws + 0x110000);   // E u32  (12.8 MB)
    int* csr   = (int*)(ws + 0xD50000);   // E ints (12.8 MB)
    u16* gb    = (u16*)(ws + 0x1990000);  // N*64 bf16 (12.8 MB) -> ends ~39.6 MB

    hipMemsetAsync(degc, 0, (size_t)N * 4, stream);

    deg_kernel<<<(E + 255) / 256, 256, 0, stream>>>(dst, degc, E);
    scanA_kernel<<<NCH, SCB, 0, stream>>>(degc, offs, csum, N);
    scanB_kernel<<<1, 256, 0, stream>>>(csum, cbase, NCH);
    scanC_kernel<<<NCH, SCB, 0, stream>>>(offs, cbase, N);
    bcini_kernel<<<1, 512, 0, stream>>>(offs, bcur, NB);
    gemm_kernel<<<(N + 63) / 64, 256, 0, stream>>>(x, W1, degc, gb, N);
    binfill_kernel<<<(E + 255) / 256, 256, 0, stream>>>(src, dst, bcur, ebuf, E);
    csrb_kernel<<<NB, 256, 0, stream>>>(ebuf, offs, csr, N, E, NB);
    agg_kernel<<<(N + 3) / 4, 256, 0, stream>>>(gb, csr, offs, degc, W2, b1, b2, out, N);
}

// Round 8
// 208.435 us; speedup vs baseline: 13.1258x; 6.6909x over previous
//
#include <hip/hip_runtime.h>

// GCN regression: out = relu( dinv⊙(A_hat @ (dinv⊙(x@W1^T))) + b1 ) @ W2^T + b2
// R6: block-aggregated partition (no per-edge global atomics).
//   1. bhist_kernel : 391-bucket edge histogram (LDS-aggregated)
//   2. bscan_kernel : scan bucket counts -> boff, bcur
//   3. part_kernel  : per-block(8192 edges) LDS histogram + scan + 1 atomic/bucket
//                     -> bucket-sorted LDS stage -> coalesced ebuf writeout
//   4. csrb2_kernel : per-bucket: node histogram+scan (writes offs/degc),
//                     LDS scatter -> coalesced CSR span write
//   5. gemm_kernel  : g = dinv ⊙ (x @ W1^T) stored bf16
//   6. agg_kernel   : wave per node, batched bf16 gathers, fused epilogue

typedef unsigned int u32;
typedef unsigned short u16;

#define PK 8192      // edges per partition block
#define CAP 12288    // max edges per 256-node bucket (mean 8192)

__device__ __forceinline__ u16 f2bf(float f) {
    u32 b = __float_as_uint(f);
    b += 0x7FFF + ((b >> 16) & 1);
    return (u16)(b >> 16);
}
__device__ __forceinline__ float bf2f(u16 u) {
    return __uint_as_float(((u32)u) << 16);
}
__device__ __forceinline__ int swz(int k, int cc) {
    int g = cc >> 2;
    int slot = (k << 4) + (g ^ (k & 15));
    return (slot << 2) + (cc & 3);
}

// ---- 1. bucket histogram ----
__global__ __launch_bounds__(256) void bhist_kernel(const int* __restrict__ dst,
                                                    int* __restrict__ bcnt,
                                                    int E, int NB) {
    __shared__ int h[512];
    int t = threadIdx.x;
    for (int i = t; i < 512; i += 256) h[i] = 0;
    __syncthreads();
    for (int e = blockIdx.x * 256 + t; e < E; e += gridDim.x * 256)
        atomicAdd(&h[dst[e] >> 8], 1);
    __syncthreads();
    for (int i = t; i < NB; i += 256)
        if (h[i]) atomicAdd(&bcnt[i], h[i]);
}

// ---- 2. bucket scan (NB <= 512) ----
__global__ __launch_bounds__(512) void bscan_kernel(const int* __restrict__ bcnt,
                                                    int* __restrict__ boff,
                                                    int* __restrict__ bcur,
                                                    int NB, int E) {
    __shared__ int buf[2][512];
    int t = threadIdx.x;
    int v = (t < NB) ? bcnt[t] : 0;
    buf[0][t] = v;
    __syncthreads();
    int pi = 0;
    for (int d = 1; d < 512; d <<= 1) {
        int val = buf[pi][t];
        if (t >= d) val += buf[pi][t - d];
        buf[pi ^ 1][t] = val;
        pi ^= 1;
        __syncthreads();
    }
    if (t < NB) {
        int excl = buf[pi][t] - v;
        boff[t] = excl;
        bcur[t] = excl;
    }
    if (t == 0) boff[NB] = E;
}

// ---- 3. chunked partition: 1 global atomic per bucket per block ----
__global__ __launch_bounds__(256) void part_kernel(const int* __restrict__ src,
                                                   const int* __restrict__ dst,
                                                   int* __restrict__ bcur,
                                                   u32* __restrict__ ebuf, int E, int NB) {
    __shared__ u32 stage[PK];     // 32 KB
    __shared__ u16 sbid[PK];      // 16 KB
    __shared__ int h[512], loff[512], gbase[512], cur[512];
    int t = threadIdx.x;
    int e0 = blockIdx.x * PK;
    int e1 = e0 + PK; if (e1 > E) e1 = E;
    int cnt = e1 - e0;
    for (int i = t; i < 512; i += 256) { h[i] = 0; cur[i] = 0; }
    __syncthreads();
    for (int e = e0 + t; e < e1; e += 256) atomicAdd(&h[dst[e] >> 8], 1);
    __syncthreads();
    if (t < 64) {                 // wave 0: scan 512 slots, carry across chunks
        int carry = 0;
        for (int c = 0; c < 8; ++c) {
            int idx = c * 64 + t;
            int v = h[idx], incl = v;
            for (int d2 = 1; d2 < 64; d2 <<= 1) {
                int o = __shfl_up(incl, d2);
                if (t >= d2) incl += o;
            }
            loff[idx] = carry + incl - v;
            carry += __shfl(incl, 63);
        }
    }
    __syncthreads();
    for (int idx = t; idx < NB; idx += 256)
        gbase[idx] = atomicAdd(&bcur[idx], h[idx]);
    __syncthreads();
    for (int e = e0 + t; e < e1; e += 256) {
        int d = dst[e], s = src[e];
        int bk = d >> 8;
        int r = atomicAdd(&cur[bk], 1);
        int p = loff[bk] + r;
        stage[p] = ((u32)(d & 255) << 17) | (u32)s;
        sbid[p] = (u16)bk;
    }
    __syncthreads();
    for (int i = t; i < cnt; i += 256) {        // coalesced runs per bucket
        int bk = sbid[i];
        ebuf[gbase[bk] + (i - loff[bk])] = stage[i];
    }
}

// ---- 4. per-bucket CSR build + offs/degc ----
__global__ __launch_bounds__(256) void csrb2_kernel(const u32* __restrict__ ebuf,
                                                    const int* __restrict__ boff,
                                                    int* __restrict__ csr,
                                                    int* __restrict__ offs,
                                                    int* __restrict__ degc,
                                                    int N) {
    __shared__ u32 stage[CAP];    // 48 KB
    __shared__ int h2[256], lofs[256], cur2[256];
    int t = threadIdx.x;
    int b = blockIdx.x;
    int base = b << 8;
    int b0 = boff[b], b1 = boff[b + 1];
    int cnt = b1 - b0;
    h2[t] = 0; cur2[t] = 0;
    __syncthreads();
    for (int e = t; e < cnt; e += 256) atomicAdd(&h2[(int)(ebuf[b0 + e] >> 17)], 1);
    __syncthreads();
    if (t < 64) {
        int carry = 0;
        for (int c = 0; c < 4; ++c) {
            int idx = c * 64 + t;
            int v = h2[idx], incl = v;
            for (int d2 = 1; d2 < 64; d2 <<= 1) {
                int o = __shfl_up(incl, d2);
                if (t >= d2) incl += o;
            }
            lofs[idx] = carry + incl - v;
            carry += __shfl(incl, 63);
        }
    }
    __syncthreads();
    int n = base + t;
    if (n < N) { offs[n] = b0 + lofs[t]; degc[n] = h2[t]; }
    if (cnt <= CAP) {
        for (int e = t; e < cnt; e += 256) {
            u32 pk = ebuf[b0 + e];
            int dl = (int)(pk >> 17);
            int r = atomicAdd(&cur2[dl], 1);
            stage[lofs[dl] + r] = pk & 0x1FFFF;
        }
        __syncthreads();
        for (int e = t; e < cnt; e += 256) csr[b0 + e] = (int)stage[e];
    } else {  // statistically unreachable fallback
        for (int e = t; e < cnt; e += 256) {
            u32 pk = ebuf[b0 + e];
            int dl = (int)(pk >> 17);
            int r = atomicAdd(&cur2[dl], 1);
            csr[b0 + lofs[dl] + r] = (int)(pk & 0x1FFFF);
        }
    }
}

// ---- 5. g = dinv * (x @ W1^T), bf16 out ----
__global__ __launch_bounds__(256) void gemm_kernel(const float* __restrict__ x,
                                                   const float* __restrict__ W1,
                                                   const int* __restrict__ degc,
                                                   u16* __restrict__ gb, int N) {
    __shared__ float xT[128 * 64];
    __shared__ float wT[128 * 64];
    int t = threadIdx.x;
    int nbase = blockIdx.x * 64;

    for (int i = t; i < 64 * 128; i += 256) {
        int c = i >> 7, k = i & 127;
        wT[swz(k, c)] = W1[i];
    }
    for (int it = 0; it < 8; ++it) {
        int node = it * 8 + (t >> 5);
        int k4 = (t & 31) << 2;
        int n = nbase + node;
        float4 v = make_float4(0.f, 0.f, 0.f, 0.f);
        if (n < N) v = *(const float4*)&x[(size_t)n * 128 + k4];
        xT[swz(k4 + 0, node)] = v.x;
        xT[swz(k4 + 1, node)] = v.y;
        xT[swz(k4 + 2, node)] = v.z;
        xT[swz(k4 + 3, node)] = v.w;
    }
    __syncthreads();

    int tx = t & 15;
    int ty = t >> 4;
    float acc[4][4] = {};
#pragma unroll 4
    for (int k = 0; k < 128; ++k) {
        float4 xv = *(const float4*)&xT[swz(k, ty << 2)];
        float4 wv = *(const float4*)&wT[swz(k, tx << 2)];
        float xa[4] = {xv.x, xv.y, xv.z, xv.w};
        float wa[4] = {wv.x, wv.y, wv.z, wv.w};
#pragma unroll
        for (int i2 = 0; i2 < 4; ++i2)
#pragma unroll
            for (int j2 = 0; j2 < 4; ++j2)
                acc[i2][j2] = fmaf(xa[i2], wa[j2], acc[i2][j2]);
    }

#pragma unroll
    for (int i2 = 0; i2 < 4; ++i2) {
        int n = nbase + (ty << 2) + i2;
        if (n < N) {
            float dv = rsqrtf((float)(degc[n] + 1));
            ushort4 o;
            o.x = f2bf(dv * acc[i2][0]);
            o.y = f2bf(dv * acc[i2][1]);
            o.z = f2bf(dv * acc[i2][2]);
            o.w = f2bf(dv * acc[i2][3]);
            *(ushort4*)&gb[(size_t)n * 64 + (tx << 2)] = o;
        }
    }
}

// ---- 6. wave per node: batched bf16 gathers, fused epilogue ----
__global__ __launch_bounds__(256) void agg_kernel(const u16* __restrict__ gb,
                                                  const int* __restrict__ csr,
                                                  const int* __restrict__ offs,
                                                  const int* __restrict__ degc,
                                                  const float* __restrict__ W2,
                                                  const float* __restrict__ b1,
                                                  const float* __restrict__ b2,
                                                  float* __restrict__ out, int N) {
    int wid = blockIdx.x * 4 + (threadIdx.x >> 6);
    int lane = threadIdx.x & 63;
    if (wid >= N) return;
    int off = offs[wid];
    int cnt = degc[wid];
    float acc = bf2f(gb[(size_t)wid * 64 + lane]);   // self loop
    for (int base = 0; base < cnt; base += 64) {
        int rem = cnt - base;
        if (rem > 64) rem = 64;
        int s = (lane < rem) ? csr[off + base + lane] : 0;
        int j = 0;
        for (; j + 8 <= rem; j += 8) {
            float v[8];
#pragma unroll
            for (int k = 0; k < 8; ++k) {
                int sj = __shfl(s, j + k);
                v[k] = bf2f(gb[(size_t)sj * 64 + lane]);
            }
            acc += ((v[0] + v[1]) + (v[2] + v[3])) + ((v[4] + v[5]) + (v[6] + v[7]));
        }
        for (; j < rem; ++j) {
            int sj = __shfl(s, j);
            acc += bf2f(gb[(size_t)sj * 64 + lane]);
        }
    }
    float dv = rsqrtf((float)(cnt + 1));
    float val = fmaxf(dv * acc + b1[lane], 0.f) * W2[lane];
#pragma unroll
    for (int o = 32; o >= 1; o >>= 1) val += __shfl_xor(val, o);
    if (lane == 0) out[wid] = val + b2[0];
}

extern "C" void kernel_launch(void* const* d_in, const int* in_sizes, int n_in,
                              void* d_out, int out_size, void* d_ws, size_t ws_size,
                              hipStream_t stream) {
    const float* x  = (const float*)d_in[0];
    const int*   ei = (const int*)d_in[1];
    const float* W1 = (const float*)d_in[2];
    const float* b1 = (const float*)d_in[3];
    const float* W2 = (const float*)d_in[4];
    const float* b2 = (const float*)d_in[5];
    float* out = (float*)d_out;

    int N = in_sizes[0] / 128;
    int E = in_sizes[1] / 2;
    const int* src = ei;
    const int* dst = ei + E;
    int NB = (N + 255) >> 8;           // 391 (<= 512)
    int NBLK = (E + PK - 1) / PK;      // 391

    char* ws = (char*)d_ws;
    int* bcnt = (int*)(ws + 0x000000);   // NB ints
    int* boff = (int*)(ws + 0x004000);   // NB+1 ints
    int* bcur = (int*)(ws + 0x008000);   // NB ints
    int* degc = (int*)(ws + 0x010000);   // N ints
    int* offs = (int*)(ws + 0x080000);   // N ints
    u32* ebuf = (u32*)(ws + 0x110000);   // E u32  (12.8 MB)
    int* csr  = (int*)(ws + 0xD50000);   // E ints (12.8 MB)
    u16* gb   = (u16*)(ws + 0x1990000);  // N*64 bf16 (12.8 MB) -> ends ~39.6 MB

    hipMemsetAsync(bcnt, 0, (size_t)NB * 4, stream);

    bhist_kernel<<<1024, 256, 0, stream>>>(dst, bcnt, E, NB);
    bscan_kernel<<<1, 512, 0, stream>>>(bcnt, boff, bcur, NB, E);
    part_kernel<<<NBLK, 256, 0, stream>>>(src, dst, bcur, ebuf, E, NB);
    csrb2_kernel<<<NB, 256, 0, stream>>>(ebuf, boff, csr, offs, degc, N);
    gemm_kernel<<<(N + 63) / 64, 256, 0, stream>>>(x, W1, degc, gb, N);
    agg_kernel<<<(N + 3) / 4, 256, 0, stream>>>(gb, csr, offs, degc, W2, b1, b2, out, N);
}

// Round 10
// 190.626 us; speedup vs baseline: 14.3521x; 1.0934x over previous
//
#include <hip/hip_runtime.h>

// GCN regression: out = relu( dinv⊙(A_hat @ (dinv⊙(x@W1^T))) + b1 ) @ W2^T + b2
// R7: slotted buckets (no global histogram pass) + wide agg gather.
//   1. init_kernel  : bcur[b] = b*CAPB (slotted ebuf cursors)
//   2. part_kernel  : per-block(8192 edges) LDS hist + scan + 1 atomic/bucket
//                     -> bucket-sorted LDS stage -> coalesced slotted-ebuf writeout
//   3. bscan2_kernel: scan (bcur[b]-b*CAPB) -> compact csr offsets boff
//   4. csrb2_kernel : per-bucket node hist+scan (offs/degc), LDS scatter ->
//                     coalesced compact CSR span
//   5. gemm_kernel  : g = dinv ⊙ (x @ W1^T) stored bf16 (aliases ebuf space)
//   6. agg_kernel   : wave per node; 8 edges x 8-channel-octet lanes ->
//                     uint4 gathers (1 KB/instr); fused epilogue

typedef unsigned int u32;
typedef unsigned short u16;

#define PK 8192      // edges per partition block
#define CAPB 9216    // slot capacity per 256-node bucket (mean 8192, +11 sigma)

__device__ __forceinline__ u16 f2bf(float f) {
    u32 b = __float_as_uint(f);
    b += 0x7FFF + ((b >> 16) & 1);
    return (u16)(b >> 16);
}
__device__ __forceinline__ float bf2f(u16 u) {
    return __uint_as_float(((u32)u) << 16);
}
__device__ __forceinline__ int swz(int k, int cc) {
    int g = cc >> 2;
    int slot = (k << 4) + (g ^ (k & 15));
    return (slot << 2) + (cc & 3);
}

// ---- 1. slotted cursor init ----
__global__ __launch_bounds__(512) void init_kernel(int* __restrict__ bcur, int NB) {
    int t = threadIdx.x;
    if (t < NB) bcur[t] = t * CAPB;
}

// ---- 2. chunked partition: 1 global atomic per bucket per block ----
__global__ __launch_bounds__(256) void part_kernel(const int* __restrict__ src,
                                                   const int* __restrict__ dst,
                                                   int* __restrict__ bcur,
                                                   u32* __restrict__ ebuf, int E, int NB) {
    __shared__ u32 stage[PK];     // 32 KB
    __shared__ u16 sbid[PK];      // 16 KB
    __shared__ int h[512], loff[512], gbase[512], cur[512];
    int t = threadIdx.x;
    int e0 = blockIdx.x * PK;
    int e1 = e0 + PK; if (e1 > E) e1 = E;
    int cnt = e1 - e0;
    for (int i = t; i < 512; i += 256) { h[i] = 0; cur[i] = 0; }
    __syncthreads();
    for (int e = e0 + t; e < e1; e += 256) atomicAdd(&h[dst[e] >> 8], 1);
    __syncthreads();
    if (t < 64) {                 // wave 0: scan 512 slots, carry across chunks
        int carry = 0;
        for (int c = 0; c < 8; ++c) {
            int idx = c * 64 + t;
            int v = h[idx], incl = v;
            for (int d2 = 1; d2 < 64; d2 <<= 1) {
                int o = __shfl_up(incl, d2);
                if (t >= d2) incl += o;
            }
            loff[idx] = carry + incl - v;
            carry += __shfl(incl, 63);
        }
    }
    __syncthreads();
    for (int idx = t; idx < NB; idx += 256)
        gbase[idx] = atomicAdd(&bcur[idx], h[idx]);
    __syncthreads();
    for (int e = e0 + t; e < e1; e += 256) {
        int d = dst[e], s = src[e];
        int bk = d >> 8;
        int r = atomicAdd(&cur[bk], 1);
        int p = loff[bk] + r;
        stage[p] = ((u32)(d & 255) << 17) | (u32)s;
        sbid[p] = (u16)bk;
    }
    __syncthreads();
    for (int i = t; i < cnt; i += 256) {        // coalesced runs per bucket
        int bk = sbid[i];
        ebuf[gbase[bk] + (i - loff[bk])] = stage[i];
    }
}

// ---- 3. compact csr offsets from slotted cursors (NB <= 512) ----
__global__ __launch_bounds__(512) void bscan2_kernel(const int* __restrict__ bcur,
                                                     int* __restrict__ boff,
                                                     int NB, int E) {
    __shared__ int buf[2][512];
    int t = threadIdx.x;
    int v = (t < NB) ? (bcur[t] - t * CAPB) : 0;
    buf[0][t] = v;
    __syncthreads();
    int pi = 0;
    for (int d = 1; d < 512; d <<= 1) {
        int val = buf[pi][t];
        if (t >= d) val += buf[pi][t - d];
        buf[pi ^ 1][t] = val;
        pi ^= 1;
        __syncthreads();
    }
    if (t < NB) boff[t] = buf[pi][t] - v;
    if (t == 0) boff[NB] = E;
}

// ---- 4. per-bucket CSR build + offs/degc ----
__global__ __launch_bounds__(256) void csrb2_kernel(const u32* __restrict__ ebuf,
                                                    const int* __restrict__ boff,
                                                    int* __restrict__ csr,
                                                    int* __restrict__ offs,
                                                    int* __restrict__ degc,
                                                    int N) {
    __shared__ u32 stage[CAPB];   // 36 KB
    __shared__ int h2[256], lofs[256], cur2[256];
    int t = threadIdx.x;
    int b = blockIdx.x;
    int base = b << 8;
    int c0 = boff[b];
    int cnt = boff[b + 1] - c0;
    int e0 = b * CAPB;
    h2[t] = 0; cur2[t] = 0;
    __syncthreads();
    for (int e = t; e < cnt; e += 256) atomicAdd(&h2[(int)(ebuf[e0 + e] >> 17)], 1);
    __syncthreads();
    if (t < 64) {
        int carry = 0;
        for (int c = 0; c < 4; ++c) {
            int idx = c * 64 + t;
            int v = h2[idx], incl = v;
            for (int d2 = 1; d2 < 64; d2 <<= 1) {
                int o = __shfl_up(incl, d2);
                if (t >= d2) incl += o;
            }
            lofs[idx] = carry + incl - v;
            carry += __shfl(incl, 63);
        }
    }
    __syncthreads();
    int n = base + t;
    if (n < N) { offs[n] = c0 + lofs[t]; degc[n] = h2[t]; }
    if (cnt <= CAPB) {
        for (int e = t; e < cnt; e += 256) {
            u32 pk = ebuf[e0 + e];
            int dl = (int)(pk >> 17);
            int r = atomicAdd(&cur2[dl], 1);
            stage[lofs[dl] + r] = pk & 0x1FFFF;
        }
        __syncthreads();
        for (int e = t; e < cnt; e += 256) csr[c0 + e] = (int)stage[e];
    } else {  // statistically unreachable fallback
        for (int e = t; e < cnt; e += 256) {
            u32 pk = ebuf[e0 + e];
            int dl = (int)(pk >> 17);
            int r = atomicAdd(&cur2[dl], 1);
            csr[c0 + lofs[dl] + r] = (int)(pk & 0x1FFFF);
        }
    }
}

// ---- 5. g = dinv * (x @ W1^T), bf16 out ----
__global__ __launch_bounds__(256) void gemm_kernel(const float* __restrict__ x,
                                                   const float* __restrict__ W1,
                                                   const int* __restrict__ degc,
                                                   u16* __restrict__ gb, int N) {
    __shared__ float xT[128 * 64];
    __shared__ float wT[128 * 64];
    int t = threadIdx.x;
    int nbase = blockIdx.x * 64;

    for (int i = t; i < 64 * 128; i += 256) {
        int c = i >> 7, k = i & 127;
        wT[swz(k, c)] = W1[i];
    }
    for (int it = 0; it < 8; ++it) {
        int node = it * 8 + (t >> 5);
        int k4 = (t & 31) << 2;
        int n = nbase + node;
        float4 v = make_float4(0.f, 0.f, 0.f, 0.f);
        if (n < N) v = *(const float4*)&x[(size_t)n * 128 + k4];
        xT[swz(k4 + 0, node)] = v.x;
        xT[swz(k4 + 1, node)] = v.y;
        xT[swz(k4 + 2, node)] = v.z;
        xT[swz(k4 + 3, node)] = v.w;
    }
    __syncthreads();

    int tx = t & 15;
    int ty = t >> 4;
    float acc[4][4] = {};
#pragma unroll 4
    for (int k = 0; k < 128; ++k) {
        float4 xv = *(const float4*)&xT[swz(k, ty << 2)];
        float4 wv = *(const float4*)&wT[swz(k, tx << 2)];
        float xa[4] = {xv.x, xv.y, xv.z, xv.w};
        float wa[4] = {wv.x, wv.y, wv.z, wv.w};
#pragma unroll
        for (int i2 = 0; i2 < 4; ++i2)
#pragma unroll
            for (int j2 = 0; j2 < 4; ++j2)
                acc[i2][j2] = fmaf(xa[i2], wa[j2], acc[i2][j2]);
    }

#pragma unroll
    for (int i2 = 0; i2 < 4; ++i2) {
        int n = nbase + (ty << 2) + i2;
        if (n < N) {
            float dv = rsqrtf((float)(degc[n] + 1));
            ushort4 o;
            o.x = f2bf(dv * acc[i2][0]);
            o.y = f2bf(dv * acc[i2][1]);
            o.z = f2bf(dv * acc[i2][2]);
            o.w = f2bf(dv * acc[i2][3]);
            *(ushort4*)&gb[(size_t)n * 64 + (tx << 2)] = o;
        }
    }
}

#define ACC8(v)                                              \
    acc[0] += __uint_as_float((v).x << 16);                  \
    acc[1] += __uint_as_float((v).x & 0xFFFF0000u);          \
    acc[2] += __uint_as_float((v).y << 16);                  \
    acc[3] += __uint_as_float((v).y & 0xFFFF0000u);          \
    acc[4] += __uint_as_float((v).z << 16);                  \
    acc[5] += __uint_as_float((v).z & 0xFFFF0000u);          \
    acc[6] += __uint_as_float((v).w << 16);                  \
    acc[7] += __uint_as_float((v).w & 0xFFFF0000u);

// ---- 6. wave per node: 8 edges x 8 channel-octets, uint4 gathers ----
__global__ __launch_bounds__(256) void agg_kernel(const u16* __restrict__ gb,
                                                  const int* __restrict__ csr,
                                                  const int* __restrict__ offs,
                                                  const int* __restrict__ degc,
                                                  const float* __restrict__ W2,
                                                  const float* __restrict__ b1,
                                                  const float* __restrict__ b2,
                                                  float* __restrict__ out, int N) {
    int wid = blockIdx.x * 4 + (threadIdx.x >> 6);
    int lane = threadIdx.x & 63;
    if (wid >= N) return;
    int r = lane >> 3;        // edge-in-batch 0..7
    int c = lane & 7;         // channel octet: chans c*8 .. c*8+7
    int off = offs[wid];
    int cnt = degc[wid];
    float acc[8] = {};
    if (r == 0) {             // self loop, counted once
        uint4 v = *(const uint4*)&gb[(size_t)wid * 64 + (c << 3)];
        ACC8(v)
    }
    int nwin = cnt >> 6;
    for (int w = 0; w < nwin; ++w) {
        int s = csr[off + (w << 6) + lane];
#pragma unroll
        for (int j0 = 0; j0 < 64; j0 += 8) {
            int sj = __shfl(s, j0 + r);
            uint4 v = *(const uint4*)&gb[(size_t)sj * 64 + (c << 3)];
            ACC8(v)
        }
    }
    int done = nwin << 6;
    int rem = cnt - done;
    if (rem > 0) {
        int s = (lane < rem) ? csr[off + done + lane] : 0;
        for (int j0 = 0; j0 < rem; j0 += 8) {
            int myj = j0 + r;
            int sj = __shfl(s, myj);
            if (myj < rem) {
                uint4 v = *(const uint4*)&gb[(size_t)sj * 64 + (c << 3)];
                ACC8(v)
            }
        }
    }
    // reduce across edge groups r (lanes differing in bits 3..5)
#pragma unroll
    for (int o = 8; o <= 32; o <<= 1) {
#pragma unroll
        for (int k = 0; k < 8; ++k) acc[k] += __shfl_xor(acc[k], o);
    }
    // epilogue: this lane's channels c*8..c*8+7
    float dv = rsqrtf((float)(cnt + 1));
    float val = 0.f;
#pragma unroll
    for (int k = 0; k < 8; ++k) {
        int ch = (c << 3) + k;
        val += fmaxf(dv * acc[k] + b1[ch], 0.f) * W2[ch];
    }
#pragma unroll
    for (int o = 1; o <= 4; o <<= 1) val += __shfl_xor(val, o);
    if (lane == 0) out[wid] = val + b2[0];
}

extern "C" void kernel_launch(void* const* d_in, const int* in_sizes, int n_in,
                              void* d_out, int out_size, void* d_ws, size_t ws_size,
                              hipStream_t stream) {
    const float* x  = (const float*)d_in[0];
    const int*   ei = (const int*)d_in[1];
    const float* W1 = (const float*)d_in[2];
    const float* b1 = (const float*)d_in[3];
    const float* W2 = (const float*)d_in[4];
    const float* b2 = (const float*)d_in[5];
    float* out = (float*)d_out;

    int N = in_sizes[0] / 128;
    int E = in_sizes[1] / 2;
    const int* src = ei;
    const int* dst = ei + E;
    int NB = (N + 255) >> 8;           // 391 (<= 512)
    int NBLK = (E + PK - 1) / PK;      // 391

    char* ws = (char*)d_ws;
    int* bcur = (int*)(ws + 0x000000);   // NB ints
    int* boff = (int*)(ws + 0x004000);   // NB+1 ints
    int* degc = (int*)(ws + 0x010000);   // N ints
    int* offs = (int*)(ws + 0x080000);   // N ints
    u32* ebuf = (u32*)(ws + 0x100000);   // NB*CAPB u32 (13.8 MB); dead after csrb2
    u16* gb   = (u16*)(ws + 0x100000);   // N*64 bf16 (12.8 MB) ALIASES ebuf
    int* csr  = (int*)(ws + 0xF00000);   // E ints (12.8 MB) -> ends ~27.2 MB

    init_kernel<<<1, 512, 0, stream>>>(bcur, NB);
    part_kernel<<<NBLK, 256, 0, stream>>>(src, dst, bcur, ebuf, E, NB);
    bscan2_kernel<<<1, 512, 0, stream>>>(bcur, boff, NB, E);
    csrb2_kernel<<<NB, 256, 0, stream>>>(ebuf, boff, csr, offs, degc, N);
    gemm_kernel<<<(N + 63) / 64, 256, 0, stream>>>(x, W1, degc, gb, N);
    agg_kernel<<<(N + 3) / 4, 256, 0, stream>>>(gb, csr, offs, degc, W2, b1, b2, out, N);
}

// Round 13
// 178.020 us; speedup vs baseline: 15.3684x; 1.0708x over previous
//
#include <hip/hip_runtime.h>

// GCN regression: out = relu( dinv⊙(A_hat @ (dinv⊙(x@W1^T))) + b1 ) @ W2^T + b2
// R8: scalar-index agg gather (SMEM csr reads, SGPR-base row loads).
//   1. init_kernel  : bcur[b] = b*CAPB (slotted ebuf cursors)
//   2. part_kernel  : per-block(8192 edges) LDS hist + scan + 1 atomic/bucket
//   3. bscan2_kernel: scan (bcur[b]-b*CAPB) -> compact csr offsets boff
//   4. csrb2_kernel : per-bucket node hist+scan (offs/degc), LDS scatter -> CSR
//   5. gemm_kernel  : g = dinv ⊙ (x @ W1^T) stored bf16 (aliases ebuf space)
//   6. agg_kernel   : wave per node; uniform csr index -> s_load; row gather
//                     via SGPR-base 2B/lane loads; fused epilogue

typedef unsigned int u32;
typedef unsigned short u16;

#define PK 8192      // edges per partition block
#define CAPB 9216    // slot capacity per 256-node bucket (mean 8192, +11 sigma)

__device__ __forceinline__ u16 f2bf(float f) {
    u32 b = __float_as_uint(f);
    b += 0x7FFF + ((b >> 16) & 1);
    return (u16)(b >> 16);
}
__device__ __forceinline__ float bf2f(u16 u) {
    return __uint_as_float(((u32)u) << 16);
}
__device__ __forceinline__ int swz(int k, int cc) {
    int g = cc >> 2;
    int slot = (k << 4) + (g ^ (k & 15));
    return (slot << 2) + (cc & 3);
}

// ---- 1. slotted cursor init ----
__global__ __launch_bounds__(512) void init_kernel(int* __restrict__ bcur, int NB) {
    int t = threadIdx.x;
    if (t < NB) bcur[t] = t * CAPB;
}

// ---- 2. chunked partition: 1 global atomic per bucket per block ----
__global__ __launch_bounds__(256) void part_kernel(const int* __restrict__ src,
                                                   const int* __restrict__ dst,
                                                   int* __restrict__ bcur,
                                                   u32* __restrict__ ebuf, int E, int NB) {
    __shared__ u32 stage[PK];     // 32 KB
    __shared__ u16 sbid[PK];      // 16 KB
    __shared__ int h[512], loff[512], gbase[512], cur[512];
    int t = threadIdx.x;
    int e0 = blockIdx.x * PK;
    int e1 = e0 + PK; if (e1 > E) e1 = E;
    int cnt = e1 - e0;
    for (int i = t; i < 512; i += 256) { h[i] = 0; cur[i] = 0; }
    __syncthreads();
    for (int e = e0 + t; e < e1; e += 256) atomicAdd(&h[dst[e] >> 8], 1);
    __syncthreads();
    if (t < 64) {                 // wave 0: scan 512 slots, carry across chunks
        int carry = 0;
        for (int c = 0; c < 8; ++c) {
            int idx = c * 64 + t;
            int v = h[idx], incl = v;
            for (int d2 = 1; d2 < 64; d2 <<= 1) {
                int o = __shfl_up(incl, d2);
                if (t >= d2) incl += o;
            }
            loff[idx] = carry + incl - v;
            carry += __shfl(incl, 63);
        }
    }
    __syncthreads();
    for (int idx = t; idx < NB; idx += 256)
        gbase[idx] = atomicAdd(&bcur[idx], h[idx]);
    __syncthreads();
    for (int e = e0 + t; e < e1; e += 256) {
        int d = dst[e], s = src[e];
        int bk = d >> 8;
        int r = atomicAdd(&cur[bk], 1);
        int p = loff[bk] + r;
        stage[p] = ((u32)(d & 255) << 17) | (u32)s;
        sbid[p] = (u16)bk;
    }
    __syncthreads();
    for (int i = t; i < cnt; i += 256) {        // coalesced runs per bucket
        int bk = sbid[i];
        ebuf[gbase[bk] + (i - loff[bk])] = stage[i];
    }
}

// ---- 3. compact csr offsets from slotted cursors (NB <= 512) ----
__global__ __launch_bounds__(512) void bscan2_kernel(const int* __restrict__ bcur,
                                                     int* __restrict__ boff,
                                                     int NB, int E) {
    __shared__ int buf[2][512];
    int t = threadIdx.x;
    int v = (t < NB) ? (bcur[t] - t * CAPB) : 0;
    buf[0][t] = v;
    __syncthreads();
    int pi = 0;
    for (int d = 1; d < 512; d <<= 1) {
        int val = buf[pi][t];
        if (t >= d) val += buf[pi][t - d];
        buf[pi ^ 1][t] = val;
        pi ^= 1;
        __syncthreads();
    }
    if (t < NB) boff[t] = buf[pi][t] - v;
    if (t == 0) boff[NB] = E;
}

// ---- 4. per-bucket CSR build + offs/degc ----
__global__ __launch_bounds__(256) void csrb2_kernel(const u32* __restrict__ ebuf,
                                                    const int* __restrict__ boff,
                                                    int* __restrict__ csr,
                                                    int* __restrict__ offs,
                                                    int* __restrict__ degc,
                                                    int N) {
    __shared__ u32 stage[CAPB];   // 36 KB
    __shared__ int h2[256], lofs[256], cur2[256];
    int t = threadIdx.x;
    int b = blockIdx.x;
    int base = b << 8;
    int c0 = boff[b];
    int cnt = boff[b + 1] - c0;
    int e0 = b * CAPB;
    h2[t] = 0; cur2[t] = 0;
    __syncthreads();
    for (int e = t; e < cnt; e += 256) atomicAdd(&h2[(int)(ebuf[e0 + e] >> 17)], 1);
    __syncthreads();
    if (t < 64) {
        int carry = 0;
        for (int c = 0; c < 4; ++c) {
            int idx = c * 64 + t;
            int v = h2[idx], incl = v;
            for (int d2 = 1; d2 < 64; d2 <<= 1) {
                int o = __shfl_up(incl, d2);
                if (t >= d2) incl += o;
            }
            lofs[idx] = carry + incl - v;
            carry += __shfl(incl, 63);
        }
    }
    __syncthreads();
    int n = base + t;
    if (n < N) { offs[n] = c0 + lofs[t]; degc[n] = h2[t]; }
    if (cnt <= CAPB) {
        for (int e = t; e < cnt; e += 256) {
            u32 pk = ebuf[e0 + e];
            int dl = (int)(pk >> 17);
            int r = atomicAdd(&cur2[dl], 1);
            stage[lofs[dl] + r] = pk & 0x1FFFF;
        }
        __syncthreads();
        for (int e = t; e < cnt; e += 256) csr[c0 + e] = (int)stage[e];
    } else {  // statistically unreachable fallback
        for (int e = t; e < cnt; e += 256) {
            u32 pk = ebuf[e0 + e];
            int dl = (int)(pk >> 17);
            int r = atomicAdd(&cur2[dl], 1);
            csr[c0 + lofs[dl] + r] = (int)(pk & 0x1FFFF);
        }
    }
}

// ---- 5. g = dinv * (x @ W1^T), bf16 out ----
__global__ __launch_bounds__(256) void gemm_kernel(const float* __restrict__ x,
                                                   const float* __restrict__ W1,
                                                   const int* __restrict__ degc,
                                                   u16* __restrict__ gb, int N) {
    __shared__ float xT[128 * 64];
    __shared__ float wT[128 * 64];
    int t = threadIdx.x;
    int nbase = blockIdx.x * 64;

    for (int i = t; i < 64 * 128; i += 256) {
        int c = i >> 7, k = i & 127;
        wT[swz(k, c)] = W1[i];
    }
    for (int it = 0; it < 8; ++it) {
        int node = it * 8 + (t >> 5);
        int k4 = (t & 31) << 2;
        int n = nbase + node;
        float4 v = make_float4(0.f, 0.f, 0.f, 0.f);
        if (n < N) v = *(const float4*)&x[(size_t)n * 128 + k4];
        xT[swz(k4 + 0, node)] = v.x;
        xT[swz(k4 + 1, node)] = v.y;
        xT[swz(k4 + 2, node)] = v.z;
        xT[swz(k4 + 3, node)] = v.w;
    }
    __syncthreads();

    int tx = t & 15;
    int ty = t >> 4;
    float acc[4][4] = {};
#pragma unroll 4
    for (int k = 0; k < 128; ++k) {
        float4 xv = *(const float4*)&xT[swz(k, ty << 2)];
        float4 wv = *(const float4*)&wT[swz(k, tx << 2)];
        float xa[4] = {xv.x, xv.y, xv.z, xv.w};
        float wa[4] = {wv.x, wv.y, wv.z, wv.w};
#pragma unroll
        for (int i2 = 0; i2 < 4; ++i2)
#pragma unroll
            for (int j2 = 0; j2 < 4; ++j2)
                acc[i2][j2] = fmaf(xa[i2], wa[j2], acc[i2][j2]);
    }

#pragma unroll
    for (int i2 = 0; i2 < 4; ++i2) {
        int n = nbase + (ty << 2) + i2;
        if (n < N) {
            float dv = rsqrtf((float)(degc[n] + 1));
            ushort4 o;
            o.x = f2bf(dv * acc[i2][0]);
            o.y = f2bf(dv * acc[i2][1]);
            o.z = f2bf(dv * acc[i2][2]);
            o.w = f2bf(dv * acc[i2][3]);
            *(ushort4*)&gb[(size_t)n * 64 + (tx << 2)] = o;
        }
    }
}

// ---- 6. wave per node: scalar csr indices (s_load), SGPR-base row gather ----
__global__ __launch_bounds__(256) void agg_kernel(const u16* __restrict__ gb,
                                                  const int* __restrict__ csr,
                                                  const int* __restrict__ offs,
                                                  const int* __restrict__ degc,
                                                  const float* __restrict__ W2,
                                                  const float* __restrict__ b1,
                                                  const float* __restrict__ b2,
                                                  float* __restrict__ out, int N) {
    int wid = blockIdx.x * 4 + (threadIdx.x >> 6);
    int lane = threadIdx.x & 63;
    if (wid >= N) return;
    // wave-uniform scalars -> SGPR: csr reads become s_load, row base SALU
    int off = __builtin_amdgcn_readfirstlane(offs[wid]);
    int cnt = __builtin_amdgcn_readfirstlane(degc[wid]);
    const u16* gbl = gb + lane;               // per-lane channel base
    float acc = bf2f(gbl[(size_t)wid * 64]);  // self loop
    int j = 0;
    for (; j + 8 <= cnt; j += 8) {
        float v[8];
#pragma unroll
        for (int k = 0; k < 8; ++k) {
            int s = csr[off + j + k];         // uniform addr -> scalar load
            v[k] = bf2f(gbl[(size_t)s * 64]);
        }
        acc += ((v[0] + v[1]) + (v[2] + v[3])) + ((v[4] + v[5]) + (v[6] + v[7]));
    }
    for (; j < cnt; ++j) {
        int s = csr[off + j];
        acc += bf2f(gbl[(size_t)s * 64]);
    }
    float dv = rsqrtf((float)(cnt + 1));
    float val = fmaxf(dv * acc + b1[lane], 0.f) * W2[lane];
#pragma unroll
    for (int o = 32; o >= 1; o >>= 1) val += __shfl_xor(val, o);
    if (lane == 0) out[wid] = val + b2[0];
}

extern "C" void kernel_launch(void* const* d_in, const int* in_sizes, int n_in,
                              void* d_out, int out_size, void* d_ws, size_t ws_size,
                              hipStream_t stream) {
    const float* x  = (const float*)d_in[0];
    const int*   ei = (const int*)d_in[1];
    const float* W1 = (const float*)d_in[2];
    const float* b1 = (const float*)d_in[3];
    const float* W2 = (const float*)d_in[4];
    const float* b2 = (const float*)d_in[5];
    float* out = (float*)d_out;

    int N = in_sizes[0] / 128;
    int E = in_sizes[1] / 2;
    const int* src = ei;
    const int* dst = ei + E;
    int NB = (N + 255) >> 8;           // 391 (<= 512)
    int NBLK = (E + PK - 1) / PK;      // 391

    char* ws = (char*)d_ws;
    int* bcur = (int*)(ws + 0x000000);   // NB ints
    int* boff = (int*)(ws + 0x004000);   // NB+1 ints
    int* degc = (int*)(ws + 0x010000);   // N ints
    int* offs = (int*)(ws + 0x080000);   // N ints
    u32* ebuf = (u32*)(ws + 0x100000);   // NB*CAPB u32 (13.8 MB); dead after csrb2
    u16* gb   = (u16*)(ws + 0x100000);   // N*64 bf16 (12.8 MB) ALIASES ebuf
    int* csr  = (int*)(ws + 0xF00000);   // E ints (12.8 MB) -> ends ~27.2 MB

    init_kernel<<<1, 512, 0, stream>>>(bcur, NB);
    part_kernel<<<NBLK, 256, 0, stream>>>(src, dst, bcur, ebuf, E, NB);
    bscan2_kernel<<<1, 512, 0, stream>>>(bcur, boff, NB, E);
    csrb2_kernel<<<NB, 256, 0, stream>>>(ebuf, boff, csr, offs, degc, N);
    gemm_kernel<<<(N + 63) / 64, 256, 0, stream>>>(x, W1, degc, gb, N);
    agg_kernel<<<(N + 3) / 4, 256, 0, stream>>>(gb, csr, offs, degc, W2, b1, b2, out, N);
}

// Round 14
// 167.500 us; speedup vs baseline: 16.3336x; 1.0628x over previous
//
#include <hip/hip_runtime.h>

// GCN regression: out = relu( dinv⊙(A_hat @ (dinv⊙(x@W1^T))) + b1 ) @ W2^T + b2
// R9: agg MLP x2 (16 gathers in flight), part dst register-staging.
//   1. init_kernel  : bcur[b] = b*CAPB (slotted ebuf cursors)
//   2. part_kernel  : per-block(8192 edges) LDS hist + scan + 1 atomic/bucket
//   3. bscan2_kernel: scan (bcur[b]-b*CAPB) -> compact csr offsets boff
//   4. csrb2_kernel : per-bucket node hist+scan (offs/degc), LDS scatter -> CSR
//   5. gemm_kernel  : g = dinv ⊙ (x @ W1^T) stored bf16 (aliases ebuf space)
//   6. agg_kernel   : wave per node; s_load_dwordx16 csr indices; 16 SGPR-base
//                     2B/lane gathers in flight; fused epilogue

typedef unsigned int u32;
typedef unsigned short u16;

#define PK 8192      // edges per partition block
#define EPT (PK/256) // edges per thread in part (32)
#define CAPB 9216    // slot capacity per 256-node bucket (mean 8192, +11 sigma)

__device__ __forceinline__ u16 f2bf(float f) {
    u32 b = __float_as_uint(f);
    b += 0x7FFF + ((b >> 16) & 1);
    return (u16)(b >> 16);
}
__device__ __forceinline__ float bf2f(u16 u) {
    return __uint_as_float(((u32)u) << 16);
}
__device__ __forceinline__ int swz(int k, int cc) {
    int g = cc >> 2;
    int slot = (k << 4) + (g ^ (k & 15));
    return (slot << 2) + (cc & 3);
}

// ---- 1. slotted cursor init ----
__global__ __launch_bounds__(512) void init_kernel(int* __restrict__ bcur, int NB) {
    int t = threadIdx.x;
    if (t < NB) bcur[t] = t * CAPB;
}

// ---- 2. chunked partition: 1 global atomic per bucket per block ----
__global__ __launch_bounds__(256) void part_kernel(const int* __restrict__ src,
                                                   const int* __restrict__ dst,
                                                   int* __restrict__ bcur,
                                                   u32* __restrict__ ebuf, int E, int NB) {
    __shared__ u32 stage[PK];     // 32 KB
    __shared__ u16 sbid[PK];      // 16 KB
    __shared__ int h[512], loff[512], gbase[512], cur[512];
    int t = threadIdx.x;
    int e0 = blockIdx.x * PK;
    int e1 = e0 + PK; if (e1 > E) e1 = E;
    int cnt = e1 - e0;
    for (int i = t; i < 512; i += 256) { h[i] = 0; cur[i] = 0; }
    __syncthreads();
    int dreg[EPT];
#pragma unroll
    for (int i = 0; i < EPT; ++i) {
        int e = e0 + i * 256 + t;
        dreg[i] = (e < e1) ? dst[e] : -1;
        if (dreg[i] >= 0) atomicAdd(&h[dreg[i] >> 8], 1);
    }
    __syncthreads();
    if (t < 64) {                 // wave 0: scan 512 slots, carry across chunks
        int carry = 0;
        for (int c = 0; c < 8; ++c) {
            int idx = c * 64 + t;
            int v = h[idx], incl = v;
            for (int d2 = 1; d2 < 64; d2 <<= 1) {
                int o = __shfl_up(incl, d2);
                if (t >= d2) incl += o;
            }
            loff[idx] = carry + incl - v;
            carry += __shfl(incl, 63);
        }
    }
    __syncthreads();
    for (int idx = t; idx < NB; idx += 256)
        gbase[idx] = atomicAdd(&bcur[idx], h[idx]);
    __syncthreads();
#pragma unroll
    for (int i = 0; i < EPT; ++i) {
        int d = dreg[i];
        if (d >= 0) {
            int e = e0 + i * 256 + t;
            int s = src[e];
            int bk = d >> 8;
            int r = atomicAdd(&cur[bk], 1);
            int p = loff[bk] + r;
            stage[p] = ((u32)(d & 255) << 17) | (u32)s;
            sbid[p] = (u16)bk;
        }
    }
    __syncthreads();
    for (int i = t; i < cnt; i += 256) {        // coalesced runs per bucket
        int bk = sbid[i];
        ebuf[gbase[bk] + (i - loff[bk])] = stage[i];
    }
}

// ---- 3. compact csr offsets from slotted cursors (NB <= 512) ----
__global__ __launch_bounds__(512) void bscan2_kernel(const int* __restrict__ bcur,
                                                     int* __restrict__ boff,
                                                     int NB, int E) {
    __shared__ int buf[2][512];
    int t = threadIdx.x;
    int v = (t < NB) ? (bcur[t] - t * CAPB) : 0;
    buf[0][t] = v;
    __syncthreads();
    int pi = 0;
    for (int d = 1; d < 512; d <<= 1) {
        int val = buf[pi][t];
        if (t >= d) val += buf[pi][t - d];
        buf[pi ^ 1][t] = val;
        pi ^= 1;
        __syncthreads();
    }
    if (t < NB) boff[t] = buf[pi][t] - v;
    if (t == 0) boff[NB] = E;
}

// ---- 4. per-bucket CSR build + offs/degc ----
__global__ __launch_bounds__(256) void csrb2_kernel(const u32* __restrict__ ebuf,
                                                    const int* __restrict__ boff,
                                                    int* __restrict__ csr,
                                                    int* __restrict__ offs,
                                                    int* __restrict__ degc,
                                                    int N) {
    __shared__ u32 stage[CAPB];   // 36 KB
    __shared__ int h2[256], lofs[256], cur2[256];
    int t = threadIdx.x;
    int b = blockIdx.x;
    int base = b << 8;
    int c0 = boff[b];
    int cnt = boff[b + 1] - c0;
    int e0 = b * CAPB;
    h2[t] = 0; cur2[t] = 0;
    __syncthreads();
    for (int e = t; e < cnt; e += 256) atomicAdd(&h2[(int)(ebuf[e0 + e] >> 17)], 1);
    __syncthreads();
    if (t < 64) {
        int carry = 0;
        for (int c = 0; c < 4; ++c) {
            int idx = c * 64 + t;
            int v = h2[idx], incl = v;
            for (int d2 = 1; d2 < 64; d2 <<= 1) {
                int o = __shfl_up(incl, d2);
                if (t >= d2) incl += o;
            }
            lofs[idx] = carry + incl - v;
            carry += __shfl(incl, 63);
        }
    }
    __syncthreads();
    int n = base + t;
    if (n < N) { offs[n] = c0 + lofs[t]; degc[n] = h2[t]; }
    if (cnt <= CAPB) {
        for (int e = t; e < cnt; e += 256) {
            u32 pk = ebuf[e0 + e];
            int dl = (int)(pk >> 17);
            int r = atomicAdd(&cur2[dl], 1);
            stage[lofs[dl] + r] = pk & 0x1FFFF;
        }
        __syncthreads();
        for (int e = t; e < cnt; e += 256) csr[c0 + e] = (int)stage[e];
    } else {  // statistically unreachable fallback
        for (int e = t; e < cnt; e += 256) {
            u32 pk = ebuf[e0 + e];
            int dl = (int)(pk >> 17);
            int r = atomicAdd(&cur2[dl], 1);
            csr[c0 + lofs[dl] + r] = (int)(pk & 0x1FFFF);
        }
    }
}

// ---- 5. g = dinv * (x @ W1^T), bf16 out ----
__global__ __launch_bounds__(256) void gemm_kernel(const float* __restrict__ x,
                                                   const float* __restrict__ W1,
                                                   const int* __restrict__ degc,
                                                   u16* __restrict__ gb, int N) {
    __shared__ float xT[128 * 64];
    __shared__ float wT[128 * 64];
    int t = threadIdx.x;
    int nbase = blockIdx.x * 64;

    for (int i = t; i < 64 * 128; i += 256) {
        int c = i >> 7, k = i & 127;
        wT[swz(k, c)] = W1[i];
    }
    for (int it = 0; it < 8; ++it) {
        int node = it * 8 + (t >> 5);
        int k4 = (t & 31) << 2;
        int n = nbase + node;
        float4 v = make_float4(0.f, 0.f, 0.f, 0.f);
        if (n < N) v = *(const float4*)&x[(size_t)n * 128 + k4];
        xT[swz(k4 + 0, node)] = v.x;
        xT[swz(k4 + 1, node)] = v.y;
        xT[swz(k4 + 2, node)] = v.z;
        xT[swz(k4 + 3, node)] = v.w;
    }
    __syncthreads();

    int tx = t & 15;
    int ty = t >> 4;
    float acc[4][4] = {};
#pragma unroll 4
    for (int k = 0; k < 128; ++k) {
        float4 xv = *(const float4*)&xT[swz(k, ty << 2)];
        float4 wv = *(const float4*)&wT[swz(k, tx << 2)];
        float xa[4] = {xv.x, xv.y, xv.z, xv.w};
        float wa[4] = {wv.x, wv.y, wv.z, wv.w};
#pragma unroll
        for (int i2 = 0; i2 < 4; ++i2)
#pragma unroll
            for (int j2 = 0; j2 < 4; ++j2)
                acc[i2][j2] = fmaf(xa[i2], wa[j2], acc[i2][j2]);
    }

#pragma unroll
    for (int i2 = 0; i2 < 4; ++i2) {
        int n = nbase + (ty << 2) + i2;
        if (n < N) {
            float dv = rsqrtf((float)(degc[n] + 1));
            ushort4 o;
            o.x = f2bf(dv * acc[i2][0]);
            o.y = f2bf(dv * acc[i2][1]);
            o.z = f2bf(dv * acc[i2][2]);
            o.w = f2bf(dv * acc[i2][3]);
            *(ushort4*)&gb[(size_t)n * 64 + (tx << 2)] = o;
        }
    }
}

// ---- 6. wave per node: s_load_dwordx16 indices, 16 gathers in flight ----
__global__ __launch_bounds__(256) void agg_kernel(const u16* __restrict__ gb,
                                                  const int* __restrict__ csr,
                                                  const int* __restrict__ offs,
                                                  const int* __restrict__ degc,
                                                  const float* __restrict__ W2,
                                                  const float* __restrict__ b1,
                                                  const float* __restrict__ b2,
                                                  float* __restrict__ out, int N) {
    int wid = blockIdx.x * 4 + (threadIdx.x >> 6);
    int lane = threadIdx.x & 63;
    if (wid >= N) return;
    // wave-uniform scalars -> SGPR: csr reads become s_load, row base SALU
    int off = __builtin_amdgcn_readfirstlane(offs[wid]);
    int cnt = __builtin_amdgcn_readfirstlane(degc[wid]);
    const u16* gbl = gb + lane;               // per-lane channel base
    float acc = bf2f(gbl[(size_t)wid * 64]);  // self loop
    int j = 0;
    for (; j + 16 <= cnt; j += 16) {
        float v[16];
#pragma unroll
        for (int k = 0; k < 16; ++k) {
            int s = csr[off + j + k];         // uniform addr -> s_load_dwordx16
            v[k] = bf2f(gbl[(size_t)s * 64]);
        }
        float s01 = (v[0] + v[1]) + (v[2] + v[3]);
        float s23 = (v[4] + v[5]) + (v[6] + v[7]);
        float s45 = (v[8] + v[9]) + (v[10] + v[11]);
        float s67 = (v[12] + v[13]) + (v[14] + v[15]);
        acc += (s01 + s23) + (s45 + s67);
    }
    for (; j + 4 <= cnt; j += 4) {
        float v[4];
#pragma unroll
        for (int k = 0; k < 4; ++k) {
            int s = csr[off + j + k];
            v[k] = bf2f(gbl[(size_t)s * 64]);
        }
        acc += (v[0] + v[1]) + (v[2] + v[3]);
    }
    for (; j < cnt; ++j) {
        int s = csr[off + j];
        acc += bf2f(gbl[(size_t)s * 64]);
    }
    float dv = rsqrtf((float)(cnt + 1));
    float val = fmaxf(dv * acc + b1[lane], 0.f) * W2[lane];
#pragma unroll
    for (int o = 32; o >= 1; o >>= 1) val += __shfl_xor(val, o);
    if (lane == 0) out[wid] = val + b2[0];
}

extern "C" void kernel_launch(void* const* d_in, const int* in_sizes, int n_in,
                              void* d_out, int out_size, void* d_ws, size_t ws_size,
                              hipStream_t stream) {
    const float* x  = (const float*)d_in[0];
    const int*   ei = (const int*)d_in[1];
    const float* W1 = (const float*)d_in[2];
    const float* b1 = (const float*)d_in[3];
    const float* W2 = (const float*)d_in[4];
    const float* b2 = (const float*)d_in[5];
    float* out = (float*)d_out;

    int N = in_sizes[0] / 128;
    int E = in_sizes[1] / 2;
    const int* src = ei;
    const int* dst = ei + E;
    int NB = (N + 255) >> 8;           // 391 (<= 512)
    int NBLK = (E + PK - 1) / PK;      // 391

    char* ws = (char*)d_ws;
    int* bcur = (int*)(ws + 0x000000);   // NB ints
    int* boff = (int*)(ws + 0x004000);   // NB+1 ints
    int* degc = (int*)(ws + 0x010000);   // N ints
    int* offs = (int*)(ws + 0x080000);   // N ints
    u32* ebuf = (u32*)(ws + 0x100000);   // NB*CAPB u32 (13.8 MB); dead after csrb2
    u16* gb   = (u16*)(ws + 0x100000);   // N*64 bf16 (12.8 MB) ALIASES ebuf
    int* csr  = (int*)(ws + 0xF00000);   // E ints (12.8 MB) -> ends ~27.2 MB

    init_kernel<<<1, 512, 0, stream>>>(bcur, NB);
    part_kernel<<<NBLK, 256, 0, stream>>>(src, dst, bcur, ebuf, E, NB);
    bscan2_kernel<<<1, 512, 0, stream>>>(bcur, boff, NB, E);
    csrb2_kernel<<<NB, 256, 0, stream>>>(ebuf, boff, csr, offs, degc, N);
    gemm_kernel<<<(N + 63) / 64, 256, 0, stream>>>(x, W1, degc, gb, N);
    agg_kernel<<<(N + 3) / 4, 256, 0, stream>>>(gb, csr, offs, degc, W2, b1, b2, out, N);
}

// Round 15
// 159.035 us; speedup vs baseline: 17.2030x; 1.0532x over previous
//
#include <hip/hip_runtime.h>

// GCN regression: out = relu( dinv⊙(A_hat @ (dinv⊙(x@W1^T))) + b1 ) @ W2^T + b2
// R10: gemm v2 — both tiles natural [row][k] layout, 16B-granular XOR swizzle
//      (conflict-free staging writes AND compute reads), float4-only LDS ops.
//   1. init_kernel  : bcur[b] = b*CAPB
//   2. part_kernel  : per-block(8192 edges) LDS hist + scan + 1 atomic/bucket
//   3. bscan2_kernel: scan -> compact csr offsets boff
//   4. csrb2_kernel : per-bucket node hist+scan (offs/degc), LDS scatter -> CSR
//   5. gemm_kernel  : g = dinv ⊙ (x @ W1^T) stored bf16
//   6. agg_kernel   : wave per node; s_load csr indices; 16 gathers in flight

typedef unsigned int u32;
typedef unsigned short u16;

#define PK 8192      // edges per partition block
#define EPT (PK/256) // edges per thread in part (32)
#define CAPB 9216    // slot capacity per 256-node bucket (mean 8192, +11 sigma)

__device__ __forceinline__ u16 f2bf(float f) {
    u32 b = __float_as_uint(f);
    b += 0x7FFF + ((b >> 16) & 1);
    return (u16)(b >> 16);
}
__device__ __forceinline__ float bf2f(u16 u) {
    return __uint_as_float(((u32)u) << 16);
}

// tile element index (in dwords) for (row r, col k) of a [64][128] f32 tile:
// 16B slot = r*32 + (q ^ swz(r)), q = k>>2; bank group (q ^ (r>>2))&7 spreads
// optimally for row-parallel staging writes and 4tx+j / 4ty+i compute reads.
__device__ __forceinline__ int tidx(int r, int k) {
    int sw = (((r & 3) << 3) | ((r >> 2) & 7));
    return (((r << 5) + ((k >> 2) ^ sw)) << 2) + (k & 3);
}

// ---- 1. slotted cursor init ----
__global__ __launch_bounds__(512) void init_kernel(int* __restrict__ bcur, int NB) {
    int t = threadIdx.x;
    if (t < NB) bcur[t] = t * CAPB;
}

// ---- 2. chunked partition: 1 global atomic per bucket per block ----
__global__ __launch_bounds__(256) void part_kernel(const int* __restrict__ src,
                                                   const int* __restrict__ dst,
                                                   int* __restrict__ bcur,
                                                   u32* __restrict__ ebuf, int E, int NB) {
    __shared__ u32 stage[PK];     // 32 KB
    __shared__ u16 sbid[PK];      // 16 KB
    __shared__ int h[512], loff[512], gbase[512], cur[512];
    int t = threadIdx.x;
    int e0 = blockIdx.x * PK;
    int e1 = e0 + PK; if (e1 > E) e1 = E;
    int cnt = e1 - e0;
    for (int i = t; i < 512; i += 256) { h[i] = 0; cur[i] = 0; }
    __syncthreads();
    int dreg[EPT];
#pragma unroll
    for (int i = 0; i < EPT; ++i) {
        int e = e0 + i * 256 + t;
        dreg[i] = (e < e1) ? dst[e] : -1;
        if (dreg[i] >= 0) atomicAdd(&h[dreg[i] >> 8], 1);
    }
    __syncthreads();
    if (t < 64) {                 // wave 0: scan 512 slots, carry across chunks
        int carry = 0;
        for (int c = 0; c < 8; ++c) {
            int idx = c * 64 + t;
            int v = h[idx], incl = v;
            for (int d2 = 1; d2 < 64; d2 <<= 1) {
                int o = __shfl_up(incl, d2);
                if (t >= d2) incl += o;
            }
            loff[idx] = carry + incl - v;
            carry += __shfl(incl, 63);
        }
    }
    __syncthreads();
    for (int idx = t; idx < NB; idx += 256)
        gbase[idx] = atomicAdd(&bcur[idx], h[idx]);
    __syncthreads();
#pragma unroll
    for (int i = 0; i < EPT; ++i) {
        int d = dreg[i];
        if (d >= 0) {
            int e = e0 + i * 256 + t;
            int s = src[e];
            int bk = d >> 8;
            int r = atomicAdd(&cur[bk], 1);
            int p = loff[bk] + r;
            stage[p] = ((u32)(d & 255) << 17) | (u32)s;
            sbid[p] = (u16)bk;
        }
    }
    __syncthreads();
    for (int i = t; i < cnt; i += 256) {        // coalesced runs per bucket
        int bk = sbid[i];
        ebuf[gbase[bk] + (i - loff[bk])] = stage[i];
    }
}

// ---- 3. compact csr offsets from slotted cursors (NB <= 512) ----
__global__ __launch_bounds__(512) void bscan2_kernel(const int* __restrict__ bcur,
                                                     int* __restrict__ boff,
                                                     int NB, int E) {
    __shared__ int buf[2][512];
    int t = threadIdx.x;
    int v = (t < NB) ? (bcur[t] - t * CAPB) : 0;
    buf[0][t] = v;
    __syncthreads();
    int pi = 0;
    for (int d = 1; d < 512; d <<= 1) {
        int val = buf[pi][t];
        if (t >= d) val += buf[pi][t - d];
        buf[pi ^ 1][t] = val;
        pi ^= 1;
        __syncthreads();
    }
    if (t < NB) boff[t] = buf[pi][t] - v;
    if (t == 0) boff[NB] = E;
}

// ---- 4. per-bucket CSR build + offs/degc ----
__global__ __launch_bounds__(256) void csrb2_kernel(const u32* __restrict__ ebuf,
                                                    const int* __restrict__ boff,
                                                    int* __restrict__ csr,
                                                    int* __restrict__ offs,
                                                    int* __restrict__ degc,
                                                    int N) {
    __shared__ u32 stage[CAPB];   // 36 KB
    __shared__ int h2[256], lofs[256], cur2[256];
    int t = threadIdx.x;
    int b = blockIdx.x;
    int base = b << 8;
    int c0 = boff[b];
    int cnt = boff[b + 1] - c0;
    int e0 = b * CAPB;
    h2[t] = 0; cur2[t] = 0;
    __syncthreads();
    for (int e = t; e < cnt; e += 256) atomicAdd(&h2[(int)(ebuf[e0 + e] >> 17)], 1);
    __syncthreads();
    if (t < 64) {
        int carry = 0;
        for (int c = 0; c < 4; ++c) {
            int idx = c * 64 + t;
            int v = h2[idx], incl = v;
            for (int d2 = 1; d2 < 64; d2 <<= 1) {
                int o = __shfl_up(incl, d2);
                if (t >= d2) incl += o;
            }
            lofs[idx] = carry + incl - v;
            carry += __shfl(incl, 63);
        }
    }
    __syncthreads();
    int n = base + t;
    if (n < N) { offs[n] = c0 + lofs[t]; degc[n] = h2[t]; }
    if (cnt <= CAPB) {
        for (int e = t; e < cnt; e += 256) {
            u32 pk = ebuf[e0 + e];
            int dl = (int)(pk >> 17);
            int r = atomicAdd(&cur2[dl], 1);
            stage[lofs[dl] + r] = pk & 0x1FFFF;
        }
        __syncthreads();
        for (int e = t; e < cnt; e += 256) csr[c0 + e] = (int)stage[e];
    } else {  // statistically unreachable fallback
        for (int e = t; e < cnt; e += 256) {
            u32 pk = ebuf[e0 + e];
            int dl = (int)(pk >> 17);
            int r = atomicAdd(&cur2[dl], 1);
            csr[c0 + lofs[dl] + r] = (int)(pk & 0x1FFFF);
        }
    }
}

// ---- 5. g = dinv * (x @ W1^T), bf16 out; swizzled [64][128] f32 tiles ----
__global__ __launch_bounds__(256) void gemm_kernel(const float* __restrict__ x,
                                                   const float* __restrict__ W1,
                                                   const int* __restrict__ degc,
                                                   u16* __restrict__ gb, int N) {
    __shared__ float xl[64 * 128];   // 32 KB, swizzled via tidx
    __shared__ float wl[64 * 128];   // 32 KB, swizzled via tidx
    int t = threadIdx.x;
    int nbase = blockIdx.x * 64;

    // stage both tiles: straight row-major copies, float4 in and out
#pragma unroll
    for (int it = 0; it < 8; ++it) {
        int qi = it * 256 + t;
        int r = qi >> 5;           // row 0..63
        int q = qi & 31;           // k-quad 0..31
        // W1 row r = channel r
        *(float4*)&wl[tidx(r, q << 2)] = *(const float4*)&W1[r * 128 + (q << 2)];
        // x row r = node nbase + r
        int n = nbase + r;
        float4 v = make_float4(0.f, 0.f, 0.f, 0.f);
        if (n < N) v = *(const float4*)&x[(size_t)n * 128 + (q << 2)];
        *(float4*)&xl[tidx(r, q << 2)] = v;
    }
    __syncthreads();

    int tx = t & 15;   // channel group: c = tx*4 .. +3
    int ty = t >> 4;   // node group:    n = ty*4 .. +3
    float acc[4][4] = {};
    for (int kq = 0; kq < 32; ++kq) {
        int k4 = kq << 2;
        float4 xa[4], wa[4];
#pragma unroll
        for (int i = 0; i < 4; ++i) xa[i] = *(const float4*)&xl[tidx((ty << 2) + i, k4)];
#pragma unroll
        for (int j = 0; j < 4; ++j) wa[j] = *(const float4*)&wl[tidx((tx << 2) + j, k4)];
#pragma unroll
        for (int i = 0; i < 4; ++i)
#pragma unroll
            for (int j = 0; j < 4; ++j) {
                acc[i][j] = fmaf(xa[i].x, wa[j].x, acc[i][j]);
                acc[i][j] = fmaf(xa[i].y, wa[j].y, acc[i][j]);
                acc[i][j] = fmaf(xa[i].z, wa[j].z, acc[i][j]);
                acc[i][j] = fmaf(xa[i].w, wa[j].w, acc[i][j]);
            }
    }

#pragma unroll
    for (int i = 0; i < 4; ++i) {
        int n = nbase + (ty << 2) + i;
        if (n < N) {
            float dv = rsqrtf((float)(degc[n] + 1));
            ushort4 o;
            o.x = f2bf(dv * acc[i][0]);
            o.y = f2bf(dv * acc[i][1]);
            o.z = f2bf(dv * acc[i][2]);
            o.w = f2bf(dv * acc[i][3]);
            *(ushort4*)&gb[(size_t)n * 64 + (tx << 2)] = o;
        }
    }
}

// ---- 6. wave per node: s_load_dwordx16 indices, 16 gathers in flight ----
__global__ __launch_bounds__(256) void agg_kernel(const u16* __restrict__ gb,
                                                  const int* __restrict__ csr,
                                                  const int* __restrict__ offs,
                                                  const int* __restrict__ degc,
                                                  const float* __restrict__ W2,
                                                  const float* __restrict__ b1,
                                                  const float* __restrict__ b2,
                                                  float* __restrict__ out, int N) {
    int wid = blockIdx.x * 4 + (threadIdx.x >> 6);
    int lane = threadIdx.x & 63;
    if (wid >= N) return;
    // wave-uniform scalars -> SGPR: csr reads become s_load, row base SALU
    int off = __builtin_amdgcn_readfirstlane(offs[wid]);
    int cnt = __builtin_amdgcn_readfirstlane(degc[wid]);
    const u16* gbl = gb + lane;               // per-lane channel base
    float acc = bf2f(gbl[(size_t)wid * 64]);  // self loop
    int j = 0;
    for (; j + 16 <= cnt; j += 16) {
        float v[16];
#pragma unroll
        for (int k = 0; k < 16; ++k) {
            int s = csr[off + j + k];         // uniform addr -> s_load_dwordx16
            v[k] = bf2f(gbl[(size_t)s * 64]);
        }
        float s01 = (v[0] + v[1]) + (v[2] + v[3]);
        float s23 = (v[4] + v[5]) + (v[6] + v[7]);
        float s45 = (v[8] + v[9]) + (v[10] + v[11]);
        float s67 = (v[12] + v[13]) + (v[14] + v[15]);
        acc += (s01 + s23) + (s45 + s67);
    }
    for (; j + 4 <= cnt; j += 4) {
        float v[4];
#pragma unroll
        for (int k = 0; k < 4; ++k) {
            int s = csr[off + j + k];
            v[k] = bf2f(gbl[(size_t)s * 64]);
        }
        acc += (v[0] + v[1]) + (v[2] + v[3]);
    }
    for (; j < cnt; ++j) {
        int s = csr[off + j];
        acc += bf2f(gbl[(size_t)s * 64]);
    }
    float dv = rsqrtf((float)(cnt + 1));
    float val = fmaxf(dv * acc + b1[lane], 0.f) * W2[lane];
#pragma unroll
    for (int o = 32; o >= 1; o >>= 1) val += __shfl_xor(val, o);
    if (lane == 0) out[wid] = val + b2[0];
}

extern "C" void kernel_launch(void* const* d_in, const int* in_sizes, int n_in,
                              void* d_out, int out_size, void* d_ws, size_t ws_size,
                              hipStream_t stream) {
    const float* x  = (const float*)d_in[0];
    const int*   ei = (const int*)d_in[1];
    const float* W1 = (const float*)d_in[2];
    const float* b1 = (const float*)d_in[3];
    const float* W2 = (const float*)d_in[4];
    const float* b2 = (const float*)d_in[5];
    float* out = (float*)d_out;

    int N = in_sizes[0] / 128;
    int E = in_sizes[1] / 2;
    const int* src = ei;
    const int* dst = ei + E;
    int NB = (N + 255) >> 8;           // 391 (<= 512)
    int NBLK = (E + PK - 1) / PK;      // 391

    char* ws = (char*)d_ws;
    int* bcur = (int*)(ws + 0x000000);   // NB ints
    int* boff = (int*)(ws + 0x004000);   // NB+1 ints
    int* degc = (int*)(ws + 0x010000);   // N ints
    int* offs = (int*)(ws + 0x080000);   // N ints
    u32* ebuf = (u32*)(ws + 0x100000);   // NB*CAPB u32 (13.8 MB); dead after csrb2
    u16* gb   = (u16*)(ws + 0x100000);   // N*64 bf16 (12.8 MB) ALIASES ebuf
    int* csr  = (int*)(ws + 0xF00000);   // E ints (12.8 MB) -> ends ~27.2 MB

    init_kernel<<<1, 512, 0, stream>>>(bcur, NB);
    part_kernel<<<NBLK, 256, 0, stream>>>(src, dst, bcur, ebuf, E, NB);
    bscan2_kernel<<<1, 512, 0, stream>>>(bcur, boff, NB, E);
    csrb2_kernel<<<NB, 256, 0, stream>>>(ebuf, boff, csr, offs, degc, N);
    gemm_kernel<<<(N + 63) / 64, 256, 0, stream>>>(x, W1, degc, gb, N);
    agg_kernel<<<(N + 3) / 4, 256, 0, stream>>>(gb, csr, offs, degc, W2, b1, b2, out, N);
}